// Round 13
// baseline (106.665 us; speedup 1.0000x reference)
//
#include <hip/hip_runtime.h>
#include <hip/hip_bf16.h>
#include <math.h>

#define B_ 2
#define T_ 2048
#define C_ 768
#define H_ 12
#define D_ 64

typedef __attribute__((ext_vector_type(8))) short short8;
typedef __attribute__((ext_vector_type(4))) float f32x4;
typedef __attribute__((ext_vector_type(16))) float f32x16;

template <bool V> struct BoolC { static constexpr bool value = V; };

#define SBAR() do { asm volatile("" ::: "memory"); __builtin_amdgcn_s_barrier(); asm volatile("" ::: "memory"); } while (0)
#define WAITVM(N) asm volatile("s_waitcnt vmcnt(" #N ")" ::: "memory")

__device__ inline unsigned short f2bf(float f) {
    unsigned int x = __float_as_uint(f);
    unsigned int r = x + 0x7FFFu + ((x >> 16) & 1u);
    return (unsigned short)(r >> 16);
}

__device__ __forceinline__ unsigned cvtpk(float lo, float hi) {
    unsigned r;
    asm("v_cvt_pk_bf16_f32 %0, %1, %2" : "=v"(r) : "v"(lo), "v"(hi));
    return r;
}

__device__ __forceinline__ void plswap(unsigned& a, unsigned& b) {
    asm volatile("v_permlane32_swap_b32 %0, %1" : "+v"(a), "+v"(b));
}

__device__ __forceinline__ void gll16(const void* g, void* l) {
    __builtin_amdgcn_global_load_lds(
        (const __attribute__((address_space(1))) unsigned int*)g,
        (__attribute__((address_space(3))) unsigned int*)l, 16, 0, 0);
}

// fused: x->bf16, Wq/Wk/Wv->wqkv bf16, Wo->wob bf16, plus coh table
__global__ __launch_bounds__(256) void convert_all_kernel(const float* __restrict__ x,
                                                          const float* __restrict__ Wq,
                                                          const float* __restrict__ Wk,
                                                          const float* __restrict__ Wv,
                                                          const float* __restrict__ Wo,
                                                          unsigned short* __restrict__ xb,
                                                          unsigned short* __restrict__ wqkv,
                                                          unsigned short* __restrict__ wob,
                                                          float* __restrict__ coh) {
    if (blockIdx.x >= 5376) {
        int dd = (blockIdx.x - 5376) * 256 + threadIdx.x;
        if (dd < T_) {
            float s = 0.f;
            for (int m = 0; m < 32; ++m) {
                float theta = powf(10000.f, -(float)m / 32.f);
                s += cosf((float)dd * theta);
            }
            coh[dd] = s * (1.f / 32.f);
        }
        return;
    }
    int i = blockIdx.x * 256 + threadIdx.x;
    float4 v;
    ushort4* d;
    if (i < 786432) {
        v = ((const float4*)x)[i];
        d = (ushort4*)xb + i;
    } else {
        int wI = i - 786432;
        int widx = wI / 147456;
        int off = wI - widx * 147456;
        const float* W = widx == 0 ? Wq : widx == 1 ? Wk : widx == 2 ? Wv : Wo;
        v = ((const float4*)W)[off];
        unsigned short* base = (widx == 3) ? wob : (wqkv + widx * 589824);
        d = (ushort4*)base + off;
    }
    ushort4 o;
    o.x = f2bf(v.x); o.y = f2bf(v.y); o.z = f2bf(v.z); o.w = f2bf(v.w);
    *d = o;
}

union QkvSmem {
    struct { unsigned short A[3][128][32]; unsigned short Bm[3][64][32]; } g;  // 36 KB
    unsigned short tr[64][136];                                               // 17.4 KB
};

// Fused QKV GEMM: 128x64 tile (one head per block), grid (32,36) = 1152 blocks.
__global__ __launch_bounds__(256, 4) void gemm_qkv_kernel(const unsigned short* __restrict__ xb,
                                                          const unsigned short* __restrict__ wqkv,
                                                          const float* __restrict__ cosb,
                                                          const float* __restrict__ sinb,
                                                          unsigned short* __restrict__ qbf,
                                                          unsigned short* __restrict__ kbf,
                                                          unsigned short* __restrict__ vt) {
    __shared__ QkvSmem sm;

    int bm = blockIdx.x, tn = blockIdx.y;
    int tid = threadIdx.x;
    int w = tid >> 6, lane = tid & 63;
    int rc = lane & 15, kg = lane >> 4;

    const unsigned short* ga = xb + (size_t)(bm * 128 + w * 32 + (lane >> 2)) * 768 + (lane & 3) * 8;
    const unsigned short* gb = wqkv + (size_t)(tn * 64 + w * 16 + (lane >> 2)) * 768 + (lane & 3) * 8;

    f32x4 acc[2][4];
    #pragma unroll
    for (int i = 0; i < 2; ++i)
        #pragma unroll
        for (int j = 0; j < 4; ++j) acc[i][j] = (f32x4){0.f, 0.f, 0.f, 0.f};

    auto stageg = [&](int buf, int k0) {
        gll16(ga + k0, &sm.g.A[buf][w * 32][0]);
        gll16(ga + k0 + 16 * 768, &sm.g.A[buf][w * 32 + 16][0]);
        gll16(gb + k0, &sm.g.Bm[buf][w * 16][0]);
    };
    auto comp = [&](int buf) {
        short8 aF[2], bF[4];
        #pragma unroll
        for (int ai = 0; ai < 2; ++ai) aF[ai] = *(const short8*)&sm.g.A[buf][w * 32 + ai * 16 + rc][kg * 8];
        #pragma unroll
        for (int bj = 0; bj < 4; ++bj) bF[bj] = *(const short8*)&sm.g.Bm[buf][bj * 16 + rc][kg * 8];
        __builtin_amdgcn_s_setprio(1);
        #pragma unroll
        for (int ai = 0; ai < 2; ++ai)
            #pragma unroll
            for (int bj = 0; bj < 4; ++bj)
                acc[ai][bj] = __builtin_amdgcn_mfma_f32_16x16x32_bf16(aF[ai], bF[bj], acc[ai][bj], 0, 0, 0);
        __builtin_amdgcn_s_setprio(0);
    };

    stageg(0, 0);
    stageg(1, 32);
    __syncthreads();
    for (int kk = 0; kk < 22; ++kk) {
        stageg((kk + 2) % 3, (kk + 2) * 32);
        WAITVM(6);
        SBAR();
        comp(kk % 3);
        SBAR();
    }
    WAITVM(3);
    SBAR();
    comp(1);   // kk = 22
    SBAR();
    WAITVM(0);
    SBAR();
    comp(2);   // kk = 23
    __syncthreads();   // before tr aliases the A/B buffers

    int tensor = tn / 12;
    int h = tn % 12;

    if (tensor < 2) {
        float scale = tensor == 0 ? 0.125f : 1.0f;
        unsigned short* dst = (tensor == 0 ? qbf : kbf);
        #pragma unroll
        for (int ai = 0; ai < 2; ++ai) {
            #pragma unroll
            for (int rr = 0; rr < 4; ++rr) {
                int m = bm * 128 + w * 32 + ai * 16 + kg * 4 + rr;
                int b = m >> 11, t = m & 2047;
                float c0 = cosb[t * 32 + rc], c1 = cosb[t * 32 + 16 + rc];
                float s0 = sinb[t * 32 + rc], s1 = sinb[t * 32 + 16 + rc];
                float x0 = acc[ai][0][rr], x1 = acc[ai][1][rr];
                float x2 = acc[ai][2][rr], x3 = acc[ai][3][rr];
                float o0 = x0 * c0 + x2 * s0;
                float o1 = x1 * c1 + x3 * s1;
                float o2 = -x0 * s0 + x2 * c0;
                float o3 = -x1 * s1 + x3 * c1;
                float ss = o0 * o0 + o1 * o1 + o2 * o2 + o3 * o3;
                ss += __shfl_xor(ss, 1); ss += __shfl_xor(ss, 2);
                ss += __shfl_xor(ss, 4); ss += __shfl_xor(ss, 8);
                float rn = rsqrtf(ss * (1.f / 64.f) + 1.1920929e-07f) * scale;
                unsigned short* dp = dst + (((size_t)b * H_ + h) * T_ + t) * 64;
                dp[rc]      = f2bf(o0 * rn);
                dp[16 + rc] = f2bf(o1 * rn);
                dp[32 + rc] = f2bf(o2 * rn);
                dp[48 + rc] = f2bf(o3 * rn);
            }
        }
    } else {
        // V: transpose via LDS, write (b,h,d,t) bf16
        #pragma unroll
        for (int ai = 0; ai < 2; ++ai)
            #pragma unroll
            for (int bj = 0; bj < 4; ++bj)
                #pragma unroll
                for (int rr = 0; rr < 4; ++rr)
                    sm.tr[bj * 16 + rc][w * 32 + ai * 16 + kg * 4 + rr] = f2bf(acc[ai][bj][rr]);
        __syncthreads();
        int m0 = bm * 128;
        int b = m0 >> 11, t0 = m0 & 2047;
        int d = w * 16 + (lane >> 2);
        int tl = (lane & 3) * 32;
        unsigned short* gp = vt + (((size_t)b * H_ + h) * 64 + d) * T_ + t0 + tl;
        #pragma unroll
        for (int i = 0; i < 4; ++i)
            *(uint4*)(gp + i * 8) = *(const uint4*)&sm.tr[d][tl + i * 8];
    }
}

// Output GEMM: 64x64 tile, grid (64,12) = 768 blocks, double-buffered.
__global__ __launch_bounds__(256, 4) void gemm_out_kernel(const unsigned short* __restrict__ A,
                                                          const unsigned short* __restrict__ Bw,
                                                          float* __restrict__ C) {
    __shared__ unsigned short lA[2][64][32];
    __shared__ unsigned short lB[2][64][32];
    int bm = blockIdx.x, tn = blockIdx.y;
    int tid = threadIdx.x;
    int w = tid >> 6, lane = tid & 63;
    int rc = lane & 15, kg = lane >> 4;
    int wr = w >> 1, wc = w & 1;

    const unsigned short* ga = A + (size_t)(bm * 64 + w * 16 + (lane >> 2)) * 768 + (lane & 3) * 8;
    const unsigned short* gbB = Bw + (size_t)(tn * 64 + w * 16 + (lane >> 2)) * 768 + (lane & 3) * 8;

    f32x4 acc[2][2];
    #pragma unroll
    for (int i = 0; i < 2; ++i)
        #pragma unroll
        for (int j = 0; j < 2; ++j) acc[i][j] = (f32x4){0.f, 0.f, 0.f, 0.f};

    auto stageg = [&](int buf, int k0) {
        gll16(ga + k0, &lA[buf][w * 16][0]);
        gll16(gbB + k0, &lB[buf][w * 16][0]);
    };
    auto comp = [&](int buf) {
        short8 aF[2], bF[2];
        #pragma unroll
        for (int ai = 0; ai < 2; ++ai) aF[ai] = *(const short8*)&lA[buf][wr * 32 + ai * 16 + rc][kg * 8];
        #pragma unroll
        for (int bj = 0; bj < 2; ++bj) bF[bj] = *(const short8*)&lB[buf][wc * 32 + bj * 16 + rc][kg * 8];
        __builtin_amdgcn_s_setprio(1);
        #pragma unroll
        for (int ai = 0; ai < 2; ++ai)
            #pragma unroll
            for (int bj = 0; bj < 2; ++bj)
                acc[ai][bj] = __builtin_amdgcn_mfma_f32_16x16x32_bf16(aF[ai], bF[bj], acc[ai][bj], 0, 0, 0);
        __builtin_amdgcn_s_setprio(0);
    };

    stageg(0, 0);
    __syncthreads();
    for (int kk = 0; kk < 23; ++kk) {
        stageg((kk + 1) & 1, (kk + 1) * 32);
        WAITVM(2);
        SBAR();
        comp(kk & 1);
        SBAR();
    }
    WAITVM(0);
    SBAR();
    comp(1);

    #pragma unroll
    for (int ai = 0; ai < 2; ++ai)
        #pragma unroll
        for (int rr = 0; rr < 4; ++rr) {
            int m = bm * 64 + wr * 32 + ai * 16 + kg * 4 + rr;
            #pragma unroll
            for (int bj = 0; bj < 2; ++bj)
                C[(size_t)m * 768 + tn * 64 + wc * 32 + bj * 16 + rc] = acc[ai][bj][rr];
        }
}

// Flash attention, split-j (flash-decoding) for long rows.
// FIX vs R12: cfl fill window lower bound is qb - te*64 + 1 (was +64 — left
// 63 entries poisoned for part-0 blocks).
__global__ __launch_bounds__(256, 4) void attn_flash_kernel(const unsigned short* __restrict__ qbf,
                                                            const unsigned short* __restrict__ kbf,
                                                            const unsigned short* __restrict__ vt,
                                                            const float* __restrict__ coh,
                                                            const float* __restrict__ beta,
                                                            unsigned short* __restrict__ yb,
                                                            float* __restrict__ po,
                                                            float* __restrict__ pz) {
    __shared__ unsigned short kT[2][64][64];
    __shared__ unsigned short vT[2][64][64];
    __shared__ float cfl[T_];

    int p = blockIdx.x;
    int xcd = p & 7, kk = p >> 3;            // kk in [0,144)
    int bl = kk / 48, u = kk % 48;
    int bh = xcd * 3 + bl;
    int tq, ts, te, part;
    if (u < 16) { tq = u; ts = 0; te = tq + 1; part = 0; }
    else {
        int idx = u - 16;                     // [0,32)
        tq = 16 + (idx >> 1);
        part = idx & 1;
        int ht = (tq + 1) >> 1;
        ts = part ? ht : 0;
        te = part ? (tq + 1) : ht;
    }
    bool hasdiag = (te == tq + 1);
    bool partial = (u >= 16);
    int b = bh / H_, h = bh % H_;

    int tid = threadIdx.x;
    int w = tid >> 6, lane = tid & 63;
    int qs = w >> 1, js = w & 1;
    int ql = lane & 31, hl = lane >> 5;

    int qb = tq * 64;
    float bv = beta[h];
    // dd window this part reads: [max(0, qb - te*64 + 1), qb + 63 - ts*64]
    int f0 = qb - te * 64 + 1;
    if (f0 < 0) f0 = 0;
    f0 >>= 2;                                 // float4 units, round down (safe)
    int f1 = (qb + 63 - ts * 64) >> 2;
    for (int i = f0 + tid; i <= f1; i += 256) {
        float4 cv = ((const float4*)coh)[i];
        float4 o;
        o.x = (1.f + bv * cv.x) * 1.4426950408889634f;
        o.y = (1.f + bv * cv.y) * 1.4426950408889634f;
        o.z = (1.f + bv * cv.z) * 1.4426950408889634f;
        o.w = (1.f + bv * cv.w) * 1.4426950408889634f;
        *(float4*)&cfl[i * 4] = o;
    }

    const unsigned short* kb = kbf + (size_t)bh * T_ * 64;
    const unsigned short* vb = vt + (size_t)bh * 64 * T_;

    const unsigned short* qrow = qbf + ((size_t)bh * T_ + qb + qs * 32 + ql) * 64 + hl * 8;
    short8 qf[4];
    #pragma unroll
    for (int d = 0; d < 4; ++d) qf[d] = *(const short8*)(qrow + d * 16);

    f32x16 acc0, acc1;
    #pragma unroll
    for (int i = 0; i < 16; ++i) { acc0[i] = 0.f; acc1[i] = 0.f; }
    float z = 0.f;

    int Rk = js * 32 + ql;
    int kby[4];
    #pragma unroll
    for (int d = 0; d < 4; ++d) kby[d] = Rk * 128 + (((d * 2 + hl) ^ (Rk & 7)) << 4);
    int vby0[2], vby1[2];
    #pragma unroll
    for (int ks = 0; ks < 2; ++ks) {
        int Rv0 = ql, Rv1 = 32 + ql;
        vby0[ks] = Rv0 * 128 + (((js * 4 + ks * 2 + hl) ^ (Rv0 & 7)) << 4);
        vby1[ks] = Rv1 * 128 + (((js * 4 + ks * 2 + hl) ^ (Rv1 & 7)) << 4);
    }
    const char* kbase = (const char*)&kT[0][0][0];
    const char* vbase = (const char*)&vT[0][0][0];

    int rloc = lane >> 3;
    int gsw = ((lane & 7) ^ rloc) * 8;
    int r0 = w * 16;

    auto stage = [&](int buf, int tj) {
        gll16(kb + (size_t)(tj + r0 + rloc) * 64 + gsw,      &kT[buf][r0][0]);
        gll16(kb + (size_t)(tj + r0 + 8 + rloc) * 64 + gsw,  &kT[buf][r0 + 8][0]);
        gll16(vb + (size_t)(r0 + rloc) * T_ + tj + gsw,      &vT[buf][r0][0]);
        gll16(vb + (size_t)(r0 + 8 + rloc) * T_ + tj + gsw,  &vT[buf][r0 + 8][0]);
    };

    int qpos = qb + qs * 32 + ql;

    auto body = [&](int buf, int tj, auto maskc) {
        constexpr bool M = decltype(maskc)::value;
        f32x16 s;
        #pragma unroll
        for (int i = 0; i < 16; ++i) s[i] = 0.f;
        const char* kp = kbase + buf * 8192;
        __builtin_amdgcn_s_setprio(1);
        #pragma unroll
        for (int d = 0; d < 4; ++d) {
            short8 kf = *(const short8*)(kp + kby[d]);
            s = __builtin_amdgcn_mfma_f32_32x32x16_bf16(kf, qf[d], s, 0, 0, 0);
        }
        __builtin_amdgcn_s_setprio(0);
        int base = qpos - tj - js * 32 - 4 * hl;
        float e[16];
        #pragma unroll
        for (int r = 0; r < 16; ++r) {
            int dd = base - ((r & 3) + 8 * (r >> 2));
            if constexpr (M) {
                float ex = __builtin_amdgcn_exp2f(s[r] * cfl[dd < 0 ? 0 : dd]);
                e[r] = dd >= 0 ? ex : 0.f;
            } else {
                e[r] = __builtin_amdgcn_exp2f(s[r] * cfl[dd]);
            }
            z += e[r];
        }
        unsigned A0 = cvtpk(e[0], e[1]),  B0 = cvtpk(e[2], e[3]);
        unsigned C0 = cvtpk(e[4], e[5]),  D0 = cvtpk(e[6], e[7]);
        unsigned E0 = cvtpk(e[8], e[9]),  F0 = cvtpk(e[10], e[11]);
        unsigned G0 = cvtpk(e[12], e[13]), H0 = cvtpk(e[14], e[15]);
        plswap(A0, C0); plswap(B0, D0); plswap(E0, G0); plswap(F0, H0);
        union U { unsigned u[4]; short8 s8; };
        U p0, p1;
        p0.u[0] = A0; p0.u[1] = B0; p0.u[2] = C0; p0.u[3] = D0;
        p1.u[0] = E0; p1.u[1] = F0; p1.u[2] = G0; p1.u[3] = H0;
        const char* vp = vbase + buf * 8192;
        short8 v00 = *(const short8*)(vp + vby0[0]);
        short8 v01 = *(const short8*)(vp + vby0[1]);
        short8 v10 = *(const short8*)(vp + vby1[0]);
        short8 v11 = *(const short8*)(vp + vby1[1]);
        __builtin_amdgcn_s_setprio(1);
        acc0 = __builtin_amdgcn_mfma_f32_32x32x16_bf16(v00, p0.s8, acc0, 0, 0, 0);
        acc0 = __builtin_amdgcn_mfma_f32_32x32x16_bf16(v01, p1.s8, acc0, 0, 0, 0);
        acc1 = __builtin_amdgcn_mfma_f32_32x32x16_bf16(v10, p0.s8, acc1, 0, 0, 0);
        acc1 = __builtin_amdgcn_mfma_f32_32x32x16_bf16(v11, p1.s8, acc1, 0, 0, 0);
        __builtin_amdgcn_s_setprio(0);
    };

    stage(0, ts * 64);
    __syncthreads();   // full drain once: buf0 + cfl + qf resolved
    int cur = 0;
    for (int it = ts; it < te - 1; ++it) {
        stage(cur ^ 1, (it + 1) * 64);
        WAITVM(4);
        SBAR();
        body(cur, it * 64, BoolC<false>{});
        SBAR();
        cur ^= 1;
    }
    WAITVM(0);
    SBAR();
    if (hasdiag) {
        // diagonal tile: qs>js full, qs==js triangular, qs<js all-masked (skip)
        if (qs > js)       body(cur, (te - 1) * 64, BoolC<false>{});
        else if (qs == js) body(cur, (te - 1) * 64, BoolC<true>{});
    } else {
        body(cur, (te - 1) * 64, BoolC<false>{});
    }
    __syncthreads();

    z += __shfl_xor(z, 32);
    float* osc = (float*)&kT[0][0][0];
    float* zbuf = (float*)&vT[0][0][0];
    if (js == 0) {
        float* o = osc + qs * 2048;
        #pragma unroll
        for (int r = 0; r < 16; ++r) {
            o[r * 64 + lane] = acc0[r];
            o[(16 + r) * 64 + lane] = acc1[r];
        }
        if (lane < 32) zbuf[qs * 32 + ql] = z;
    }
    __syncthreads();
    if (js == 1) {
        float zsum = z + zbuf[qs * 32 + ql];
        const float* o = osc + qs * 2048;
        if (!partial) {
            float invz = 1.f / zsum;
            #pragma unroll
            for (int r = 0; r < 16; ++r) {
                acc0[r] = (acc0[r] + o[r * 64 + lane]) * invz;
                acc1[r] = (acc1[r] + o[(16 + r) * 64 + lane]) * invz;
            }
            int t = qb + qs * 32 + ql;
            unsigned short* yp = yb + (((size_t)b * T_ + t) * H_ + h) * 64;
            #pragma unroll
            for (int g = 0; g < 4; ++g) {
                uint2 st0, st1;
                st0.x = cvtpk(acc0[g * 4 + 0], acc0[g * 4 + 1]);
                st0.y = cvtpk(acc0[g * 4 + 2], acc0[g * 4 + 3]);
                *(uint2*)(yp + g * 8 + 4 * hl) = st0;
                st1.x = cvtpk(acc1[g * 4 + 0], acc1[g * 4 + 1]);
                st1.y = cvtpk(acc1[g * 4 + 2], acc1[g * 4 + 3]);
                *(uint2*)(yp + 32 + g * 8 + 4 * hl) = st1;
            }
        } else {
            int slot = (bh * 16 + (tq - 16)) * 2 + part;
            float* pob = po + (size_t)slot * 4096 + qs * 2048;
            #pragma unroll
            for (int r = 0; r < 16; ++r) {
                pob[r * 64 + lane] = acc0[r] + o[r * 64 + lane];
                pob[(16 + r) * 64 + lane] = acc1[r] + o[(16 + r) * 64 + lane];
            }
            if (hl == 0) pz[slot * 64 + qs * 32 + ql] = zsum;
        }
    }
}

// combine two j-half partials per (bh, tq>=16): O = (p0+p1)/(z0+z1) -> yb bf16
__global__ __launch_bounds__(256) void attn_combine_kernel(const float* __restrict__ po,
                                                           const float* __restrict__ pz,
                                                           unsigned short* __restrict__ yb) {
    int cb = blockIdx.x;               // [0, 384): bh*16 + (tq-16)
    int bh = cb >> 4;
    int tq = 16 + (cb & 15);
    int b = bh / H_, h = bh % H_;
    const float* p0 = po + (size_t)cb * 8192;
    const float* p1 = p0 + 4096;
    const float* z0 = pz + (size_t)cb * 128;
    const float* z1 = z0 + 64;
    for (int e = threadIdx.x; e < 4096; e += 256) {
        int qs = e >> 11, r = (e >> 6) & 31, lane = e & 63;
        int ql = lane & 31, hl = lane >> 5;
        int row = qs * 32 + ql;
        float invz = 1.f / (z0[row] + z1[row]);
        int rb = r & 15;
        int d = ((r >> 4) << 5) + ((rb >> 2) << 3) + (hl << 2) + (rb & 3);
        float val = (p0[e] + p1[e]) * invz;
        int t = tq * 64 + row;
        yb[(((size_t)b * T_ + t) * H_ + h) * 64 + d] = f2bf(val);
    }
}

extern "C" void kernel_launch(void* const* d_in, const int* in_sizes, int n_in,
                              void* d_out, int out_size, void* d_ws, size_t ws_size,
                              hipStream_t stream) {
    const float* x    = (const float*)d_in[0];
    const float* cosb = (const float*)d_in[1];
    const float* sinb = (const float*)d_in[2];
    const float* Wq   = (const float*)d_in[3];
    const float* Wk   = (const float*)d_in[4];
    const float* Wv   = (const float*)d_in[5];
    const float* Wo   = (const float*)d_in[6];
    const float* beta = (const float*)d_in[7];
    float* out = (float*)d_out;

    char* ws = (char*)d_ws;
    unsigned short* xb   = (unsigned short*)(ws + 0);
    unsigned short* wqkv = (unsigned short*)(ws + 6291456);
    unsigned short* wob  = (unsigned short*)(ws + 9830400);
    unsigned short* qbf  = (unsigned short*)(ws + 11010048);
    unsigned short* kbf  = (unsigned short*)(ws + 17301504);
    unsigned short* vt   = (unsigned short*)(ws + 23592960);
    unsigned short* yb   = (unsigned short*)(ws + 29884416);
    float*          coh  = (float*)(ws + 36175872);           // 8192 B
    float*          po   = (float*)(ws + 36184064);           // 12,582,912 B
    float*          pz   = (float*)(ws + 48766976);           // 196,608 B

    convert_all_kernel<<<5384, 256, 0, stream>>>(x, Wq, Wk, Wv, Wo, xb, wqkv, wob, coh);

    dim3 gq(32, 36);
    gemm_qkv_kernel<<<gq, 256, 0, stream>>>(xb, wqkv, cosb, sinb, qbf, kbf, vt);

    attn_flash_kernel<<<1152, 256, 0, stream>>>(qbf, kbf, vt, coh, beta, yb, po, pz);
    attn_combine_kernel<<<384, 256, 0, stream>>>(po, pz, yb);

    dim3 go(64, 12);
    gemm_out_kernel<<<go, 256, 0, stream>>>(yb, wob, out);
}

// Round 14
// 96.527 us; speedup vs baseline: 1.1050x; 1.1050x over previous
//
#include <hip/hip_runtime.h>
#include <hip/hip_bf16.h>
#include <math.h>

#define B_ 2
#define T_ 2048
#define C_ 768
#define H_ 12
#define D_ 64

typedef __attribute__((ext_vector_type(8))) short short8;
typedef __attribute__((ext_vector_type(4))) float f32x4;
typedef __attribute__((ext_vector_type(16))) float f32x16;

template <bool V> struct BoolC { static constexpr bool value = V; };

#define SBAR() do { asm volatile("" ::: "memory"); __builtin_amdgcn_s_barrier(); asm volatile("" ::: "memory"); } while (0)
#define WAITVM(N) asm volatile("s_waitcnt vmcnt(" #N ")" ::: "memory")

__device__ inline unsigned short f2bf(float f) {
    unsigned int x = __float_as_uint(f);
    unsigned int r = x + 0x7FFFu + ((x >> 16) & 1u);
    return (unsigned short)(r >> 16);
}

__device__ __forceinline__ unsigned cvtpk(float lo, float hi) {
    unsigned r;
    asm("v_cvt_pk_bf16_f32 %0, %1, %2" : "=v"(r) : "v"(lo), "v"(hi));
    return r;
}

__device__ __forceinline__ void plswap(unsigned& a, unsigned& b) {
    asm volatile("v_permlane32_swap_b32 %0, %1" : "+v"(a), "+v"(b));
}

__device__ __forceinline__ void gll16(const void* g, void* l) {
    __builtin_amdgcn_global_load_lds(
        (const __attribute__((address_space(1))) unsigned int*)g,
        (__attribute__((address_space(3))) unsigned int*)l, 16, 0, 0);
}

// fused: x->bf16, Wq/Wk/Wv->wqkv bf16, Wo->wob bf16, plus coh table
__global__ __launch_bounds__(256) void convert_all_kernel(const float* __restrict__ x,
                                                          const float* __restrict__ Wq,
                                                          const float* __restrict__ Wk,
                                                          const float* __restrict__ Wv,
                                                          const float* __restrict__ Wo,
                                                          unsigned short* __restrict__ xb,
                                                          unsigned short* __restrict__ wqkv,
                                                          unsigned short* __restrict__ wob,
                                                          float* __restrict__ coh) {
    if (blockIdx.x >= 5376) {
        int dd = (blockIdx.x - 5376) * 256 + threadIdx.x;
        if (dd < T_) {
            float s = 0.f;
            for (int m = 0; m < 32; ++m) {
                float theta = powf(10000.f, -(float)m / 32.f);
                s += cosf((float)dd * theta);
            }
            coh[dd] = s * (1.f / 32.f);
        }
        return;
    }
    int i = blockIdx.x * 256 + threadIdx.x;
    float4 v;
    ushort4* d;
    if (i < 786432) {
        v = ((const float4*)x)[i];
        d = (ushort4*)xb + i;
    } else {
        int wI = i - 786432;
        int widx = wI / 147456;
        int off = wI - widx * 147456;
        const float* W = widx == 0 ? Wq : widx == 1 ? Wk : widx == 2 ? Wv : Wo;
        v = ((const float4*)W)[off];
        unsigned short* base = (widx == 3) ? wob : (wqkv + widx * 589824);
        d = (ushort4*)base + off;
    }
    ushort4 o;
    o.x = f2bf(v.x); o.y = f2bf(v.y); o.z = f2bf(v.z); o.w = f2bf(v.w);
    *d = o;
}

union QkvSmem {
    struct { unsigned short A[3][128][32]; unsigned short Bm[3][64][32]; } g;  // 36 KB
    unsigned short tr[64][136];                                               // 17.4 KB
};

// Fused QKV GEMM: 128x64 tile (one head per block), grid (32,36) = 1152 blocks.
// Triple-buffered, single-barrier-per-step: {WAITVM(3); SBAR; stage(kk+2); comp(kk)}.
__global__ __launch_bounds__(256, 4) void gemm_qkv_kernel(const unsigned short* __restrict__ xb,
                                                          const unsigned short* __restrict__ wqkv,
                                                          const float* __restrict__ cosb,
                                                          const float* __restrict__ sinb,
                                                          unsigned short* __restrict__ qbf,
                                                          unsigned short* __restrict__ kbf,
                                                          unsigned short* __restrict__ vt) {
    __shared__ QkvSmem sm;

    int bm = blockIdx.x, tn = blockIdx.y;
    int tid = threadIdx.x;
    int w = tid >> 6, lane = tid & 63;
    int rc = lane & 15, kg = lane >> 4;

    const unsigned short* ga = xb + (size_t)(bm * 128 + w * 32 + (lane >> 2)) * 768 + (lane & 3) * 8;
    const unsigned short* gb = wqkv + (size_t)(tn * 64 + w * 16 + (lane >> 2)) * 768 + (lane & 3) * 8;

    f32x4 acc[2][4];
    #pragma unroll
    for (int i = 0; i < 2; ++i)
        #pragma unroll
        for (int j = 0; j < 4; ++j) acc[i][j] = (f32x4){0.f, 0.f, 0.f, 0.f};

    auto stageg = [&](int buf, int k0) {
        gll16(ga + k0, &sm.g.A[buf][w * 32][0]);
        gll16(ga + k0 + 16 * 768, &sm.g.A[buf][w * 32 + 16][0]);
        gll16(gb + k0, &sm.g.Bm[buf][w * 16][0]);
    };
    auto comp = [&](int buf) {
        short8 aF[2], bF[4];
        #pragma unroll
        for (int ai = 0; ai < 2; ++ai) aF[ai] = *(const short8*)&sm.g.A[buf][w * 32 + ai * 16 + rc][kg * 8];
        #pragma unroll
        for (int bj = 0; bj < 4; ++bj) bF[bj] = *(const short8*)&sm.g.Bm[buf][bj * 16 + rc][kg * 8];
        __builtin_amdgcn_s_setprio(1);
        #pragma unroll
        for (int ai = 0; ai < 2; ++ai)
            #pragma unroll
            for (int bj = 0; bj < 4; ++bj)
                acc[ai][bj] = __builtin_amdgcn_mfma_f32_16x16x32_bf16(aF[ai], bF[bj], acc[ai][bj], 0, 0, 0);
        __builtin_amdgcn_s_setprio(0);
    };

    stageg(0, 0);
    stageg(1, 32);
    __syncthreads();
    for (int kk = 0; kk < 22; ++kk) {
        WAITVM(3);                            // retire stage(kk); stage(kk+1) may stay in flight
        SBAR();                               // all waves: buf kk ready, comp(kk-1) done
        stageg((kk + 2) % 3, (kk + 2) * 32);  // overwrites buf of comp(kk-1)
        comp(kk % 3);
    }
    WAITVM(3);
    SBAR();
    comp(1);   // kk = 22
    WAITVM(0);
    SBAR();
    comp(2);   // kk = 23
    __syncthreads();   // before tr aliases the A/B buffers

    int tensor = tn / 12;
    int h = tn % 12;

    if (tensor < 2) {
        float scale = tensor == 0 ? 0.125f : 1.0f;
        unsigned short* dst = (tensor == 0 ? qbf : kbf);
        #pragma unroll
        for (int ai = 0; ai < 2; ++ai) {
            #pragma unroll
            for (int rr = 0; rr < 4; ++rr) {
                int m = bm * 128 + w * 32 + ai * 16 + kg * 4 + rr;
                int b = m >> 11, t = m & 2047;
                float c0 = cosb[t * 32 + rc], c1 = cosb[t * 32 + 16 + rc];
                float s0 = sinb[t * 32 + rc], s1 = sinb[t * 32 + 16 + rc];
                float x0 = acc[ai][0][rr], x1 = acc[ai][1][rr];
                float x2 = acc[ai][2][rr], x3 = acc[ai][3][rr];
                float o0 = x0 * c0 + x2 * s0;
                float o1 = x1 * c1 + x3 * s1;
                float o2 = -x0 * s0 + x2 * c0;
                float o3 = -x1 * s1 + x3 * c1;
                float ss = o0 * o0 + o1 * o1 + o2 * o2 + o3 * o3;
                ss += __shfl_xor(ss, 1); ss += __shfl_xor(ss, 2);
                ss += __shfl_xor(ss, 4); ss += __shfl_xor(ss, 8);
                float rn = rsqrtf(ss * (1.f / 64.f) + 1.1920929e-07f) * scale;
                unsigned short* dp = dst + (((size_t)b * H_ + h) * T_ + t) * 64;
                dp[rc]      = f2bf(o0 * rn);
                dp[16 + rc] = f2bf(o1 * rn);
                dp[32 + rc] = f2bf(o2 * rn);
                dp[48 + rc] = f2bf(o3 * rn);
            }
        }
    } else {
        // V: transpose via LDS, write (b,h,d,t) bf16
        #pragma unroll
        for (int ai = 0; ai < 2; ++ai)
            #pragma unroll
            for (int bj = 0; bj < 4; ++bj)
                #pragma unroll
                for (int rr = 0; rr < 4; ++rr)
                    sm.tr[bj * 16 + rc][w * 32 + ai * 16 + kg * 4 + rr] = f2bf(acc[ai][bj][rr]);
        __syncthreads();
        int m0 = bm * 128;
        int b = m0 >> 11, t0 = m0 & 2047;
        int d = w * 16 + (lane >> 2);
        int tl = (lane & 3) * 32;
        unsigned short* gp = vt + (((size_t)b * H_ + h) * 64 + d) * T_ + t0 + tl;
        #pragma unroll
        for (int i = 0; i < 4; ++i)
            *(uint4*)(gp + i * 8) = *(const uint4*)&sm.tr[d][tl + i * 8];
    }
}

// Output GEMM: 64x64 tile, grid (64,12), double-buffered, single barrier/step.
__global__ __launch_bounds__(256, 4) void gemm_out_kernel(const unsigned short* __restrict__ A,
                                                          const unsigned short* __restrict__ Bw,
                                                          float* __restrict__ C) {
    __shared__ unsigned short lA[2][64][32];
    __shared__ unsigned short lB[2][64][32];
    int bm = blockIdx.x, tn = blockIdx.y;
    int tid = threadIdx.x;
    int w = tid >> 6, lane = tid & 63;
    int rc = lane & 15, kg = lane >> 4;
    int wr = w >> 1, wc = w & 1;

    const unsigned short* ga = A + (size_t)(bm * 64 + w * 16 + (lane >> 2)) * 768 + (lane & 3) * 8;
    const unsigned short* gbB = Bw + (size_t)(tn * 64 + w * 16 + (lane >> 2)) * 768 + (lane & 3) * 8;

    f32x4 acc[2][2];
    #pragma unroll
    for (int i = 0; i < 2; ++i)
        #pragma unroll
        for (int j = 0; j < 2; ++j) acc[i][j] = (f32x4){0.f, 0.f, 0.f, 0.f};

    auto stageg = [&](int buf, int k0) {
        gll16(ga + k0, &lA[buf][w * 16][0]);
        gll16(gbB + k0, &lB[buf][w * 16][0]);
    };
    auto comp = [&](int buf) {
        short8 aF[2], bF[2];
        #pragma unroll
        for (int ai = 0; ai < 2; ++ai) aF[ai] = *(const short8*)&lA[buf][wr * 32 + ai * 16 + rc][kg * 8];
        #pragma unroll
        for (int bj = 0; bj < 2; ++bj) bF[bj] = *(const short8*)&lB[buf][wc * 32 + bj * 16 + rc][kg * 8];
        __builtin_amdgcn_s_setprio(1);
        #pragma unroll
        for (int ai = 0; ai < 2; ++ai)
            #pragma unroll
            for (int bj = 0; bj < 2; ++bj)
                acc[ai][bj] = __builtin_amdgcn_mfma_f32_16x16x32_bf16(aF[ai], bF[bj], acc[ai][bj], 0, 0, 0);
        __builtin_amdgcn_s_setprio(0);
    };

    stageg(0, 0);
    __syncthreads();
    for (int kk = 0; kk < 23; ++kk) {
        WAITVM(0);                            // retire stage(kk) (own loads only in flight)
        SBAR();                               // all waves: buf ready, comp(kk-1) done
        stageg((kk + 1) & 1, (kk + 1) * 32);  // overwrites buf of comp(kk-1)
        comp(kk & 1);
    }
    WAITVM(0);
    SBAR();
    comp(1);

    #pragma unroll
    for (int ai = 0; ai < 2; ++ai)
        #pragma unroll
        for (int rr = 0; rr < 4; ++rr) {
            int m = bm * 64 + wr * 32 + ai * 16 + kg * 4 + rr;
            #pragma unroll
            for (int bj = 0; bj < 2; ++bj)
                C[(size_t)m * 768 + tn * 64 + wc * 32 + bj * 16 + rc] = acc[ai][bj][rr];
        }
}

// Flash attention (R9 structure: 768 blocks, scramble mapping, dbuf staging)
// with single-barrier-per-body loop: {WAITVM(0); SBAR; stage(next); body(cur)}.
__global__ __launch_bounds__(256, 4) void attn_flash_kernel(const unsigned short* __restrict__ qbf,
                                                            const unsigned short* __restrict__ kbf,
                                                            const unsigned short* __restrict__ vt,
                                                            const float* __restrict__ coh,
                                                            const float* __restrict__ beta,
                                                            unsigned short* __restrict__ yb) {
    __shared__ unsigned short kT[2][64][64];
    __shared__ unsigned short vT[2][64][64];
    __shared__ float cfl[T_];

    int p = blockIdx.x;
    int xcd = p & 7, kk = p >> 3;
    int bl = kk >> 5, jsl = kk & 31;
    int bh = xcd * 3 + bl;
    int jj = (bl == 0) ? jsl : (bl == 1 ? (31 - jsl) : ((jsl * 5 + 3) & 31));
    int tq = 31 - jj;
    int b = bh / H_, h = bh % H_;

    int tid = threadIdx.x;
    int w = tid >> 6, lane = tid & 63;
    int qs = w >> 1, js = w & 1;
    int ql = lane & 31, hl = lane >> 5;

    float bv = beta[h];
    int cmax4 = (tq + 1) * 16;   // float4 count of used cfl range
    for (int i = tid; i < cmax4; i += 256) {
        float4 cv = ((const float4*)coh)[i];
        float4 o;
        o.x = (1.f + bv * cv.x) * 1.4426950408889634f;
        o.y = (1.f + bv * cv.y) * 1.4426950408889634f;
        o.z = (1.f + bv * cv.z) * 1.4426950408889634f;
        o.w = (1.f + bv * cv.w) * 1.4426950408889634f;
        *(float4*)&cfl[i * 4] = o;
    }

    int qb = tq * 64;
    const unsigned short* kb = kbf + (size_t)bh * T_ * 64;
    const unsigned short* vb = vt + (size_t)bh * 64 * T_;

    const unsigned short* qrow = qbf + ((size_t)bh * T_ + qb + qs * 32 + ql) * 64 + hl * 8;
    short8 qf[4];
    #pragma unroll
    for (int d = 0; d < 4; ++d) qf[d] = *(const short8*)(qrow + d * 16);

    f32x16 acc0, acc1;
    #pragma unroll
    for (int i = 0; i < 16; ++i) { acc0[i] = 0.f; acc1[i] = 0.f; }
    float z = 0.f;

    int Rk = js * 32 + ql;
    int kby[4];
    #pragma unroll
    for (int d = 0; d < 4; ++d) kby[d] = Rk * 128 + (((d * 2 + hl) ^ (Rk & 7)) << 4);
    int vby0[2], vby1[2];
    #pragma unroll
    for (int ks = 0; ks < 2; ++ks) {
        int Rv0 = ql, Rv1 = 32 + ql;
        vby0[ks] = Rv0 * 128 + (((js * 4 + ks * 2 + hl) ^ (Rv0 & 7)) << 4);
        vby1[ks] = Rv1 * 128 + (((js * 4 + ks * 2 + hl) ^ (Rv1 & 7)) << 4);
    }
    const char* kbase = (const char*)&kT[0][0][0];
    const char* vbase = (const char*)&vT[0][0][0];

    int rloc = lane >> 3;
    int gsw = ((lane & 7) ^ rloc) * 8;
    int r0 = w * 16;

    auto stage = [&](int buf, int tj) {
        gll16(kb + (size_t)(tj + r0 + rloc) * 64 + gsw,      &kT[buf][r0][0]);
        gll16(kb + (size_t)(tj + r0 + 8 + rloc) * 64 + gsw,  &kT[buf][r0 + 8][0]);
        gll16(vb + (size_t)(r0 + rloc) * T_ + tj + gsw,      &vT[buf][r0][0]);
        gll16(vb + (size_t)(r0 + 8 + rloc) * T_ + tj + gsw,  &vT[buf][r0 + 8][0]);
    };

    int qpos = qb + qs * 32 + ql;

    auto body = [&](int buf, int tj, auto maskc) {
        constexpr bool M = decltype(maskc)::value;
        f32x16 s;
        #pragma unroll
        for (int i = 0; i < 16; ++i) s[i] = 0.f;
        const char* kp = kbase + buf * 8192;
        __builtin_amdgcn_s_setprio(1);
        #pragma unroll
        for (int d = 0; d < 4; ++d) {
            short8 kf = *(const short8*)(kp + kby[d]);
            s = __builtin_amdgcn_mfma_f32_32x32x16_bf16(kf, qf[d], s, 0, 0, 0);
        }
        __builtin_amdgcn_s_setprio(0);
        int base = qpos - tj - js * 32 - 4 * hl;
        float e[16];
        #pragma unroll
        for (int r = 0; r < 16; ++r) {
            int dd = base - ((r & 3) + 8 * (r >> 2));
            if constexpr (M) {
                float ex = __builtin_amdgcn_exp2f(s[r] * cfl[dd < 0 ? 0 : dd]);
                e[r] = dd >= 0 ? ex : 0.f;
            } else {
                e[r] = __builtin_amdgcn_exp2f(s[r] * cfl[dd]);
            }
            z += e[r];
        }
        unsigned A0 = cvtpk(e[0], e[1]),  B0 = cvtpk(e[2], e[3]);
        unsigned C0 = cvtpk(e[4], e[5]),  D0 = cvtpk(e[6], e[7]);
        unsigned E0 = cvtpk(e[8], e[9]),  F0 = cvtpk(e[10], e[11]);
        unsigned G0 = cvtpk(e[12], e[13]), H0 = cvtpk(e[14], e[15]);
        plswap(A0, C0); plswap(B0, D0); plswap(E0, G0); plswap(F0, H0);
        union U { unsigned u[4]; short8 s8; };
        U p0, p1;
        p0.u[0] = A0; p0.u[1] = B0; p0.u[2] = C0; p0.u[3] = D0;
        p1.u[0] = E0; p1.u[1] = F0; p1.u[2] = G0; p1.u[3] = H0;
        const char* vp = vbase + buf * 8192;
        short8 v00 = *(const short8*)(vp + vby0[0]);
        short8 v01 = *(const short8*)(vp + vby0[1]);
        short8 v10 = *(const short8*)(vp + vby1[0]);
        short8 v11 = *(const short8*)(vp + vby1[1]);
        __builtin_amdgcn_s_setprio(1);
        acc0 = __builtin_amdgcn_mfma_f32_32x32x16_bf16(v00, p0.s8, acc0, 0, 0, 0);
        acc0 = __builtin_amdgcn_mfma_f32_32x32x16_bf16(v01, p1.s8, acc0, 0, 0, 0);
        acc1 = __builtin_amdgcn_mfma_f32_32x32x16_bf16(v10, p0.s8, acc1, 0, 0, 0);
        acc1 = __builtin_amdgcn_mfma_f32_32x32x16_bf16(v11, p1.s8, acc1, 0, 0, 0);
        __builtin_amdgcn_s_setprio(0);
    };

    int nt = tq + 1;
    stage(0, 0);
    __syncthreads();   // full drain once: buf0 + cfl + qf resolved
    int cur = 0;
    for (int it = 0; it < nt - 1; ++it) {
        WAITVM(0);                      // retire own stage(cur) loads (no-op at it=0)
        SBAR();                         // all waves: buf cur staged, body(it-1) done
        stage(cur ^ 1, (it + 1) * 64);  // overwrites buf read in body(it-1) — safe
        body(cur, it * 64, BoolC<false>{});
        cur ^= 1;
    }
    WAITVM(0);
    SBAR();
    // diagonal tile: qs>js full, qs==js triangular, qs<js all-masked (skip)
    if (qs > js)      body(cur, (nt - 1) * 64, BoolC<false>{});
    else if (qs == js) body(cur, (nt - 1) * 64, BoolC<true>{});
    __syncthreads();

    z += __shfl_xor(z, 32);
    float* osc = (float*)&kT[0][0][0];
    float* zbuf = (float*)&vT[0][0][0];
    if (js == 0) {
        float* o = osc + qs * 2048;
        #pragma unroll
        for (int r = 0; r < 16; ++r) {
            o[r * 64 + lane] = acc0[r];
            o[(16 + r) * 64 + lane] = acc1[r];
        }
        if (lane < 32) zbuf[qs * 32 + ql] = z;
    }
    __syncthreads();
    if (js == 1) {
        float zt = z + zbuf[qs * 32 + ql];
        float invz = 1.f / zt;
        const float* o = osc + qs * 2048;
        #pragma unroll
        for (int r = 0; r < 16; ++r) {
            acc0[r] = (acc0[r] + o[r * 64 + lane]) * invz;
            acc1[r] = (acc1[r] + o[(16 + r) * 64 + lane]) * invz;
        }
        int t = qb + qs * 32 + ql;
        unsigned short* yp = yb + (((size_t)b * T_ + t) * H_ + h) * 64;
        #pragma unroll
        for (int g = 0; g < 4; ++g) {
            uint2 st0, st1;
            st0.x = cvtpk(acc0[g * 4 + 0], acc0[g * 4 + 1]);
            st0.y = cvtpk(acc0[g * 4 + 2], acc0[g * 4 + 3]);
            *(uint2*)(yp + g * 8 + 4 * hl) = st0;
            st1.x = cvtpk(acc1[g * 4 + 0], acc1[g * 4 + 1]);
            st1.y = cvtpk(acc1[g * 4 + 2], acc1[g * 4 + 3]);
            *(uint2*)(yp + 32 + g * 8 + 4 * hl) = st1;
        }
    }
}

extern "C" void kernel_launch(void* const* d_in, const int* in_sizes, int n_in,
                              void* d_out, int out_size, void* d_ws, size_t ws_size,
                              hipStream_t stream) {
    const float* x    = (const float*)d_in[0];
    const float* cosb = (const float*)d_in[1];
    const float* sinb = (const float*)d_in[2];
    const float* Wq   = (const float*)d_in[3];
    const float* Wk   = (const float*)d_in[4];
    const float* Wv   = (const float*)d_in[5];
    const float* Wo   = (const float*)d_in[6];
    const float* beta = (const float*)d_in[7];
    float* out = (float*)d_out;

    char* ws = (char*)d_ws;
    unsigned short* xb   = (unsigned short*)(ws + 0);
    unsigned short* wqkv = (unsigned short*)(ws + 6291456);
    unsigned short* wob  = (unsigned short*)(ws + 9830400);
    unsigned short* qbf  = (unsigned short*)(ws + 11010048);
    unsigned short* kbf  = (unsigned short*)(ws + 17301504);
    unsigned short* vt   = (unsigned short*)(ws + 23592960);
    unsigned short* yb   = (unsigned short*)(ws + 29884416);
    float*          coh  = (float*)(ws + 36175872);

    convert_all_kernel<<<5384, 256, 0, stream>>>(x, Wq, Wk, Wv, Wo, xb, wqkv, wob, coh);

    dim3 gq(32, 36);
    gemm_qkv_kernel<<<gq, 256, 0, stream>>>(xb, wqkv, cosb, sinb, qbf, kbf, vt);

    attn_flash_kernel<<<B_ * H_ * (T_ / 64), 256, 0, stream>>>(qbf, kbf, vt, coh, beta, yb);

    dim3 go(64, 12);
    gemm_out_kernel<<<go, 256, 0, stream>>>(yb, wob, out);
}

// Round 15
// 96.510 us; speedup vs baseline: 1.1052x; 1.0002x over previous
//
#include <hip/hip_runtime.h>
#include <hip/hip_bf16.h>
#include <math.h>

#define B_ 2
#define T_ 2048
#define C_ 768
#define H_ 12
#define D_ 64

typedef __attribute__((ext_vector_type(8))) short short8;
typedef __attribute__((ext_vector_type(4))) float f32x4;
typedef __attribute__((ext_vector_type(16))) float f32x16;

template <bool V> struct BoolC { static constexpr bool value = V; };

#define SBAR() do { asm volatile("" ::: "memory"); __builtin_amdgcn_s_barrier(); asm volatile("" ::: "memory"); } while (0)
#define WAITVM(N) asm volatile("s_waitcnt vmcnt(" #N ")" ::: "memory")

__device__ inline unsigned short f2bf(float f) {
    unsigned int x = __float_as_uint(f);
    unsigned int r = x + 0x7FFFu + ((x >> 16) & 1u);
    return (unsigned short)(r >> 16);
}

__device__ __forceinline__ unsigned cvtpk(float lo, float hi) {
    unsigned r;
    asm("v_cvt_pk_bf16_f32 %0, %1, %2" : "=v"(r) : "v"(lo), "v"(hi));
    return r;
}

__device__ __forceinline__ void plswap(unsigned& a, unsigned& b) {
    asm volatile("v_permlane32_swap_b32 %0, %1" : "+v"(a), "+v"(b));
}

__device__ __forceinline__ void gll16(const void* g, void* l) {
    __builtin_amdgcn_global_load_lds(
        (const __attribute__((address_space(1))) unsigned int*)g,
        (__attribute__((address_space(3))) unsigned int*)l, 16, 0, 0);
}

// fused: x->bf16, Wq/Wk/Wv->wqkv bf16, Wo->wob bf16, plus coh table
__global__ __launch_bounds__(256) void convert_all_kernel(const float* __restrict__ x,
                                                          const float* __restrict__ Wq,
                                                          const float* __restrict__ Wk,
                                                          const float* __restrict__ Wv,
                                                          const float* __restrict__ Wo,
                                                          unsigned short* __restrict__ xb,
                                                          unsigned short* __restrict__ wqkv,
                                                          unsigned short* __restrict__ wob,
                                                          float* __restrict__ coh) {
    if (blockIdx.x >= 5376) {
        int dd = (blockIdx.x - 5376) * 256 + threadIdx.x;
        if (dd < T_) {
            float s = 0.f;
            for (int m = 0; m < 32; ++m) {
                float theta = powf(10000.f, -(float)m / 32.f);
                s += cosf((float)dd * theta);
            }
            coh[dd] = s * (1.f / 32.f);
        }
        return;
    }
    int i = blockIdx.x * 256 + threadIdx.x;
    float4 v;
    ushort4* d;
    if (i < 786432) {
        v = ((const float4*)x)[i];
        d = (ushort4*)xb + i;
    } else {
        int wI = i - 786432;
        int widx = wI / 147456;
        int off = wI - widx * 147456;
        const float* W = widx == 0 ? Wq : widx == 1 ? Wk : widx == 2 ? Wv : Wo;
        v = ((const float4*)W)[off];
        unsigned short* base = (widx == 3) ? wob : (wqkv + widx * 589824);
        d = (ushort4*)base + off;
    }
    ushort4 o;
    o.x = f2bf(v.x); o.y = f2bf(v.y); o.z = f2bf(v.z); o.w = f2bf(v.w);
    *d = o;
}

union QkvSmem {
    struct { unsigned short A[3][128][32]; unsigned short Bm[3][64][32]; } g;  // 36 KB
    unsigned short tr[64][136];                                               // 17.4 KB
};

// Fused QKV GEMM: 128x64 tile (one head per block), grid (32,36) = 1152 blocks.
// Triple-buffered, single-barrier-per-step: {WAITVM(3); SBAR; stage(kk+2); comp(kk)}.
__global__ __launch_bounds__(256, 4) void gemm_qkv_kernel(const unsigned short* __restrict__ xb,
                                                          const unsigned short* __restrict__ wqkv,
                                                          const float* __restrict__ cosb,
                                                          const float* __restrict__ sinb,
                                                          unsigned short* __restrict__ qbf,
                                                          unsigned short* __restrict__ kbf,
                                                          unsigned short* __restrict__ vt) {
    __shared__ QkvSmem sm;

    int bm = blockIdx.x, tn = blockIdx.y;
    int tid = threadIdx.x;
    int w = tid >> 6, lane = tid & 63;
    int rc = lane & 15, kg = lane >> 4;

    const unsigned short* ga = xb + (size_t)(bm * 128 + w * 32 + (lane >> 2)) * 768 + (lane & 3) * 8;
    const unsigned short* gb = wqkv + (size_t)(tn * 64 + w * 16 + (lane >> 2)) * 768 + (lane & 3) * 8;

    f32x4 acc[2][4];
    #pragma unroll
    for (int i = 0; i < 2; ++i)
        #pragma unroll
        for (int j = 0; j < 4; ++j) acc[i][j] = (f32x4){0.f, 0.f, 0.f, 0.f};

    auto stageg = [&](int buf, int k0) {
        gll16(ga + k0, &sm.g.A[buf][w * 32][0]);
        gll16(ga + k0 + 16 * 768, &sm.g.A[buf][w * 32 + 16][0]);
        gll16(gb + k0, &sm.g.Bm[buf][w * 16][0]);
    };
    auto comp = [&](int buf) {
        short8 aF[2], bF[4];
        #pragma unroll
        for (int ai = 0; ai < 2; ++ai) aF[ai] = *(const short8*)&sm.g.A[buf][w * 32 + ai * 16 + rc][kg * 8];
        #pragma unroll
        for (int bj = 0; bj < 4; ++bj) bF[bj] = *(const short8*)&sm.g.Bm[buf][bj * 16 + rc][kg * 8];
        __builtin_amdgcn_s_setprio(1);
        #pragma unroll
        for (int ai = 0; ai < 2; ++ai)
            #pragma unroll
            for (int bj = 0; bj < 4; ++bj)
                acc[ai][bj] = __builtin_amdgcn_mfma_f32_16x16x32_bf16(aF[ai], bF[bj], acc[ai][bj], 0, 0, 0);
        __builtin_amdgcn_s_setprio(0);
    };

    stageg(0, 0);
    stageg(1, 32);
    __syncthreads();
    for (int kk = 0; kk < 22; ++kk) {
        WAITVM(3);                            // retire stage(kk); stage(kk+1) may stay in flight
        SBAR();                               // all waves: buf kk ready, comp(kk-1) done
        stageg((kk + 2) % 3, (kk + 2) * 32);  // overwrites buf of comp(kk-1)
        comp(kk % 3);
    }
    WAITVM(3);
    SBAR();
    comp(1);   // kk = 22
    WAITVM(0);
    SBAR();
    comp(2);   // kk = 23
    __syncthreads();   // before tr aliases the A/B buffers

    int tensor = tn / 12;
    int h = tn % 12;

    if (tensor < 2) {
        float scale = tensor == 0 ? 0.125f : 1.0f;
        unsigned short* dst = (tensor == 0 ? qbf : kbf);
        #pragma unroll
        for (int ai = 0; ai < 2; ++ai) {
            #pragma unroll
            for (int rr = 0; rr < 4; ++rr) {
                int m = bm * 128 + w * 32 + ai * 16 + kg * 4 + rr;
                int b = m >> 11, t = m & 2047;
                float c0 = cosb[t * 32 + rc], c1 = cosb[t * 32 + 16 + rc];
                float s0 = sinb[t * 32 + rc], s1 = sinb[t * 32 + 16 + rc];
                float x0 = acc[ai][0][rr], x1 = acc[ai][1][rr];
                float x2 = acc[ai][2][rr], x3 = acc[ai][3][rr];
                float o0 = x0 * c0 + x2 * s0;
                float o1 = x1 * c1 + x3 * s1;
                float o2 = -x0 * s0 + x2 * c0;
                float o3 = -x1 * s1 + x3 * c1;
                float ss = o0 * o0 + o1 * o1 + o2 * o2 + o3 * o3;
                ss += __shfl_xor(ss, 1); ss += __shfl_xor(ss, 2);
                ss += __shfl_xor(ss, 4); ss += __shfl_xor(ss, 8);
                float rn = rsqrtf(ss * (1.f / 64.f) + 1.1920929e-07f) * scale;
                unsigned short* dp = dst + (((size_t)b * H_ + h) * T_ + t) * 64;
                dp[rc]      = f2bf(o0 * rn);
                dp[16 + rc] = f2bf(o1 * rn);
                dp[32 + rc] = f2bf(o2 * rn);
                dp[48 + rc] = f2bf(o3 * rn);
            }
        }
    } else {
        // V: transpose via LDS, write (b,h,d,t) bf16
        #pragma unroll
        for (int ai = 0; ai < 2; ++ai)
            #pragma unroll
            for (int bj = 0; bj < 4; ++bj)
                #pragma unroll
                for (int rr = 0; rr < 4; ++rr)
                    sm.tr[bj * 16 + rc][w * 32 + ai * 16 + kg * 4 + rr] = f2bf(acc[ai][bj][rr]);
        __syncthreads();
        int m0 = bm * 128;
        int b = m0 >> 11, t0 = m0 & 2047;
        int d = w * 16 + (lane >> 2);
        int tl = (lane & 3) * 32;
        unsigned short* gp = vt + (((size_t)b * H_ + h) * 64 + d) * T_ + t0 + tl;
        #pragma unroll
        for (int i = 0; i < 4; ++i)
            *(uint4*)(gp + i * 8) = *(const uint4*)&sm.tr[d][tl + i * 8];
    }
}

// Output GEMM: 64x64 tile, grid (64,12), TRIPLE-buffered counted pipeline
// (mirror of gemm_qkv's verified loop; stage latency gets 2 bodies).
__global__ __launch_bounds__(256, 4) void gemm_out_kernel(const unsigned short* __restrict__ A,
                                                          const unsigned short* __restrict__ Bw,
                                                          float* __restrict__ C) {
    __shared__ unsigned short lA[3][64][32];
    __shared__ unsigned short lB[3][64][32];
    int bm = blockIdx.x, tn = blockIdx.y;
    int tid = threadIdx.x;
    int w = tid >> 6, lane = tid & 63;
    int rc = lane & 15, kg = lane >> 4;
    int wr = w >> 1, wc = w & 1;

    const unsigned short* ga = A + (size_t)(bm * 64 + w * 16 + (lane >> 2)) * 768 + (lane & 3) * 8;
    const unsigned short* gbB = Bw + (size_t)(tn * 64 + w * 16 + (lane >> 2)) * 768 + (lane & 3) * 8;

    f32x4 acc[2][2];
    #pragma unroll
    for (int i = 0; i < 2; ++i)
        #pragma unroll
        for (int j = 0; j < 2; ++j) acc[i][j] = (f32x4){0.f, 0.f, 0.f, 0.f};

    auto stageg = [&](int buf, int k0) {
        gll16(ga + k0, &lA[buf][w * 16][0]);
        gll16(gbB + k0, &lB[buf][w * 16][0]);
    };
    auto comp = [&](int buf) {
        short8 aF[2], bF[2];
        #pragma unroll
        for (int ai = 0; ai < 2; ++ai) aF[ai] = *(const short8*)&lA[buf][wr * 32 + ai * 16 + rc][kg * 8];
        #pragma unroll
        for (int bj = 0; bj < 2; ++bj) bF[bj] = *(const short8*)&lB[buf][wc * 32 + bj * 16 + rc][kg * 8];
        __builtin_amdgcn_s_setprio(1);
        #pragma unroll
        for (int ai = 0; ai < 2; ++ai)
            #pragma unroll
            for (int bj = 0; bj < 2; ++bj)
                acc[ai][bj] = __builtin_amdgcn_mfma_f32_16x16x32_bf16(aF[ai], bF[bj], acc[ai][bj], 0, 0, 0);
        __builtin_amdgcn_s_setprio(0);
    };

    stageg(0, 0);
    stageg(1, 32);
    __syncthreads();
    for (int kk = 0; kk < 22; ++kk) {
        WAITVM(2);                            // retire stage(kk); stage(kk+1) stays in flight
        SBAR();                               // all waves: buf kk ready, comp(kk-1) done
        stageg((kk + 2) % 3, (kk + 2) * 32);  // overwrites buf of comp(kk-1)
        comp(kk % 3);
    }
    WAITVM(2);
    SBAR();
    comp(1);   // kk = 22
    WAITVM(0);
    SBAR();
    comp(2);   // kk = 23

    #pragma unroll
    for (int ai = 0; ai < 2; ++ai)
        #pragma unroll
        for (int rr = 0; rr < 4; ++rr) {
            int m = bm * 64 + wr * 32 + ai * 16 + kg * 4 + rr;
            #pragma unroll
            for (int bj = 0; bj < 2; ++bj)
                C[(size_t)m * 768 + tn * 64 + wc * 32 + bj * 16 + rc] = acc[ai][bj][rr];
        }
}

// Flash attention (R14 structure) + stage(0) issued before cfl fill so the
// first K/V tile's loads fly under the table-build work.
__global__ __launch_bounds__(256, 4) void attn_flash_kernel(const unsigned short* __restrict__ qbf,
                                                            const unsigned short* __restrict__ kbf,
                                                            const unsigned short* __restrict__ vt,
                                                            const float* __restrict__ coh,
                                                            const float* __restrict__ beta,
                                                            unsigned short* __restrict__ yb) {
    __shared__ unsigned short kT[2][64][64];
    __shared__ unsigned short vT[2][64][64];
    __shared__ float cfl[T_];

    int p = blockIdx.x;
    int xcd = p & 7, kk = p >> 3;
    int bl = kk >> 5, jsl = kk & 31;
    int bh = xcd * 3 + bl;
    int jj = (bl == 0) ? jsl : (bl == 1 ? (31 - jsl) : ((jsl * 5 + 3) & 31));
    int tq = 31 - jj;
    int b = bh / H_, h = bh % H_;

    int tid = threadIdx.x;
    int w = tid >> 6, lane = tid & 63;
    int qs = w >> 1, js = w & 1;
    int ql = lane & 31, hl = lane >> 5;

    int qb = tq * 64;
    const unsigned short* kb = kbf + (size_t)bh * T_ * 64;
    const unsigned short* vb = vt + (size_t)bh * 64 * T_;

    int rloc = lane >> 3;
    int gsw = ((lane & 7) ^ rloc) * 8;
    int r0 = w * 16;

    auto stage = [&](int buf, int tj) {
        gll16(kb + (size_t)(tj + r0 + rloc) * 64 + gsw,      &kT[buf][r0][0]);
        gll16(kb + (size_t)(tj + r0 + 8 + rloc) * 64 + gsw,  &kT[buf][r0 + 8][0]);
        gll16(vb + (size_t)(r0 + rloc) * T_ + tj + gsw,      &vT[buf][r0][0]);
        gll16(vb + (size_t)(r0 + 8 + rloc) * T_ + tj + gsw,  &vT[buf][r0 + 8][0]);
    };

    stage(0, 0);   // issue first K/V tile before the cfl fill (latency overlap)

    float bv = beta[h];
    int cmax4 = (tq + 1) * 16;   // float4 count of used cfl range
    for (int i = tid; i < cmax4; i += 256) {
        float4 cv = ((const float4*)coh)[i];
        float4 o;
        o.x = (1.f + bv * cv.x) * 1.4426950408889634f;
        o.y = (1.f + bv * cv.y) * 1.4426950408889634f;
        o.z = (1.f + bv * cv.z) * 1.4426950408889634f;
        o.w = (1.f + bv * cv.w) * 1.4426950408889634f;
        *(float4*)&cfl[i * 4] = o;
    }

    const unsigned short* qrow = qbf + ((size_t)bh * T_ + qb + qs * 32 + ql) * 64 + hl * 8;
    short8 qf[4];
    #pragma unroll
    for (int d = 0; d < 4; ++d) qf[d] = *(const short8*)(qrow + d * 16);

    f32x16 acc0, acc1;
    #pragma unroll
    for (int i = 0; i < 16; ++i) { acc0[i] = 0.f; acc1[i] = 0.f; }
    float z = 0.f;

    int Rk = js * 32 + ql;
    int kby[4];
    #pragma unroll
    for (int d = 0; d < 4; ++d) kby[d] = Rk * 128 + (((d * 2 + hl) ^ (Rk & 7)) << 4);
    int vby0[2], vby1[2];
    #pragma unroll
    for (int ks = 0; ks < 2; ++ks) {
        int Rv0 = ql, Rv1 = 32 + ql;
        vby0[ks] = Rv0 * 128 + (((js * 4 + ks * 2 + hl) ^ (Rv0 & 7)) << 4);
        vby1[ks] = Rv1 * 128 + (((js * 4 + ks * 2 + hl) ^ (Rv1 & 7)) << 4);
    }
    const char* kbase = (const char*)&kT[0][0][0];
    const char* vbase = (const char*)&vT[0][0][0];

    int qpos = qb + qs * 32 + ql;

    auto body = [&](int buf, int tj, auto maskc) {
        constexpr bool M = decltype(maskc)::value;
        f32x16 s;
        #pragma unroll
        for (int i = 0; i < 16; ++i) s[i] = 0.f;
        const char* kp = kbase + buf * 8192;
        __builtin_amdgcn_s_setprio(1);
        #pragma unroll
        for (int d = 0; d < 4; ++d) {
            short8 kf = *(const short8*)(kp + kby[d]);
            s = __builtin_amdgcn_mfma_f32_32x32x16_bf16(kf, qf[d], s, 0, 0, 0);
        }
        __builtin_amdgcn_s_setprio(0);
        int base = qpos - tj - js * 32 - 4 * hl;
        float e[16];
        #pragma unroll
        for (int r = 0; r < 16; ++r) {
            int dd = base - ((r & 3) + 8 * (r >> 2));
            if constexpr (M) {
                float ex = __builtin_amdgcn_exp2f(s[r] * cfl[dd < 0 ? 0 : dd]);
                e[r] = dd >= 0 ? ex : 0.f;
            } else {
                e[r] = __builtin_amdgcn_exp2f(s[r] * cfl[dd]);
            }
            z += e[r];
        }
        unsigned A0 = cvtpk(e[0], e[1]),  B0 = cvtpk(e[2], e[3]);
        unsigned C0 = cvtpk(e[4], e[5]),  D0 = cvtpk(e[6], e[7]);
        unsigned E0 = cvtpk(e[8], e[9]),  F0 = cvtpk(e[10], e[11]);
        unsigned G0 = cvtpk(e[12], e[13]), H0 = cvtpk(e[14], e[15]);
        plswap(A0, C0); plswap(B0, D0); plswap(E0, G0); plswap(F0, H0);
        union U { unsigned u[4]; short8 s8; };
        U p0, p1;
        p0.u[0] = A0; p0.u[1] = B0; p0.u[2] = C0; p0.u[3] = D0;
        p1.u[0] = E0; p1.u[1] = F0; p1.u[2] = G0; p1.u[3] = H0;
        const char* vp = vbase + buf * 8192;
        short8 v00 = *(const short8*)(vp + vby0[0]);
        short8 v01 = *(const short8*)(vp + vby0[1]);
        short8 v10 = *(const short8*)(vp + vby1[0]);
        short8 v11 = *(const short8*)(vp + vby1[1]);
        __builtin_amdgcn_s_setprio(1);
        acc0 = __builtin_amdgcn_mfma_f32_32x32x16_bf16(v00, p0.s8, acc0, 0, 0, 0);
        acc0 = __builtin_amdgcn_mfma_f32_32x32x16_bf16(v01, p1.s8, acc0, 0, 0, 0);
        acc1 = __builtin_amdgcn_mfma_f32_32x32x16_bf16(v10, p0.s8, acc1, 0, 0, 0);
        acc1 = __builtin_amdgcn_mfma_f32_32x32x16_bf16(v11, p1.s8, acc1, 0, 0, 0);
        __builtin_amdgcn_s_setprio(0);
    };

    int nt = tq + 1;
    __syncthreads();   // full drain once: buf0 + cfl + qf resolved
    int cur = 0;
    for (int it = 0; it < nt - 1; ++it) {
        WAITVM(0);                      // retire own stage(cur) loads (no-op at it=0)
        SBAR();                         // all waves: buf cur staged, body(it-1) done
        stage(cur ^ 1, (it + 1) * 64);  // overwrites buf read in body(it-1) — safe
        body(cur, it * 64, BoolC<false>{});
        cur ^= 1;
    }
    WAITVM(0);
    SBAR();
    // diagonal tile: qs>js full, qs==js triangular, qs<js all-masked (skip)
    if (qs > js)      body(cur, (nt - 1) * 64, BoolC<false>{});
    else if (qs == js) body(cur, (nt - 1) * 64, BoolC<true>{});
    __syncthreads();

    z += __shfl_xor(z, 32);
    float* osc = (float*)&kT[0][0][0];
    float* zbuf = (float*)&vT[0][0][0];
    if (js == 0) {
        float* o = osc + qs * 2048;
        #pragma unroll
        for (int r = 0; r < 16; ++r) {
            o[r * 64 + lane] = acc0[r];
            o[(16 + r) * 64 + lane] = acc1[r];
        }
        if (lane < 32) zbuf[qs * 32 + ql] = z;
    }
    __syncthreads();
    if (js == 1) {
        float zt = z + zbuf[qs * 32 + ql];
        float invz = 1.f / zt;
        const float* o = osc + qs * 2048;
        #pragma unroll
        for (int r = 0; r < 16; ++r) {
            acc0[r] = (acc0[r] + o[r * 64 + lane]) * invz;
            acc1[r] = (acc1[r] + o[(16 + r) * 64 + lane]) * invz;
        }
        int t = qb + qs * 32 + ql;
        unsigned short* yp = yb + (((size_t)b * T_ + t) * H_ + h) * 64;
        #pragma unroll
        for (int g = 0; g < 4; ++g) {
            uint2 st0, st1;
            st0.x = cvtpk(acc0[g * 4 + 0], acc0[g * 4 + 1]);
            st0.y = cvtpk(acc0[g * 4 + 2], acc0[g * 4 + 3]);
            *(uint2*)(yp + g * 8 + 4 * hl) = st0;
            st1.x = cvtpk(acc1[g * 4 + 0], acc1[g * 4 + 1]);
            st1.y = cvtpk(acc1[g * 4 + 2], acc1[g * 4 + 3]);
            *(uint2*)(yp + 32 + g * 8 + 4 * hl) = st1;
        }
    }
}

extern "C" void kernel_launch(void* const* d_in, const int* in_sizes, int n_in,
                              void* d_out, int out_size, void* d_ws, size_t ws_size,
                              hipStream_t stream) {
    const float* x    = (const float*)d_in[0];
    const float* cosb = (const float*)d_in[1];
    const float* sinb = (const float*)d_in[2];
    const float* Wq   = (const float*)d_in[3];
    const float* Wk   = (const float*)d_in[4];
    const float* Wv   = (const float*)d_in[5];
    const float* Wo   = (const float*)d_in[6];
    const float* beta = (const float*)d_in[7];
    float* out = (float*)d_out;

    char* ws = (char*)d_ws;
    unsigned short* xb   = (unsigned short*)(ws + 0);
    unsigned short* wqkv = (unsigned short*)(ws + 6291456);
    unsigned short* wob  = (unsigned short*)(ws + 9830400);
    unsigned short* qbf  = (unsigned short*)(ws + 11010048);
    unsigned short* kbf  = (unsigned short*)(ws + 17301504);
    unsigned short* vt   = (unsigned short*)(ws + 23592960);
    unsigned short* yb   = (unsigned short*)(ws + 29884416);
    float*          coh  = (float*)(ws + 36175872);

    convert_all_kernel<<<5384, 256, 0, stream>>>(x, Wq, Wk, Wv, Wo, xb, wqkv, wob, coh);

    dim3 gq(32, 36);
    gemm_qkv_kernel<<<gq, 256, 0, stream>>>(xb, wqkv, cosb, sinb, qbf, kbf, vt);

    attn_flash_kernel<<<B_ * H_ * (T_ / 64), 256, 0, stream>>>(qbf, kbf, vt, coh, beta, yb);

    dim3 go(64, 12);
    gemm_out_kernel<<<go, 256, 0, stream>>>(yb, wob, out);
}